// Round 6
// baseline (2314.140 us; speedup 1.0000x reference)
//
#include <hip/hip_runtime.h>

// B=256, T=512, I=64, H=512.  h_t = tanh(xh_t + h@Whh); out = h_T@fc_w.T + fc_b
//
// R6 "rnn_mfma4": R5 was LDS-return-bus bound (256 KB/step/CU: A-frag broadcast delivery
// 128 KB + LDS-resident B-frags 128 KB -> ~2-3k cyc/step vs 620 cyc MFMA issue).
// A-traffic scales with #waves (each wave must receive all 16 k-tiles' A-frags:
// 16 KB/wave/step). So: 4 fat waves (256 thr, waves_per_eu(1,1) -> 512 reg slots/wave),
// each owning 128 cols = 8 nt x 16 kt. A-traffic halves to 64 KB/step. B: 12 kt in
// registers (384 slots; AGPR placement is free for MFMA operands), 4 kt in LDS (128 KB).
// Same validated MFMA fragment mappings as R5. One barrier/step.

#define BATCH    256
#define TSTEPS   512
#define IDIM     64
#define HDIM     512
#define NTH      256
#define WAVES    4
#define NT       8            // n-tiles per wave (16 cols each) -> 128 cols/wave
#define RKT      12           // k-tiles with B-frags in registers
#define LKT      4            // k-tiles with B-frags in LDS
#define KT       16           // total k-tiles (K=512)

#define LDSW_BYTES (WAVES * NT * LKT * 64 * 16)   // 131072
#define HB_OFF     LDSW_BYTES                     // 2 x 512 fp16 = 2048 B
#define RED_OFF    (HB_OFF + 2 * HDIM * 2)
#define SMEM_BYTES (RED_OFF + 64)                 // 133184 <= 160K

typedef _Float16 half2_t  __attribute__((ext_vector_type(2)));
typedef _Float16 half8_t  __attribute__((ext_vector_type(8)));
typedef float    float4_t __attribute__((ext_vector_type(4)));

union H8U {
    half8_t  v;
    half2_t  p[4];
    uint4    u4;
    _Float16 e[8];
};

__device__ __forceinline__ float fast_tanh(float x) {
    float e = __builtin_amdgcn_exp2f(x * 2.88539008177792681472f);
    return 1.0f - 2.0f * __builtin_amdgcn_rcpf(e + 1.0f);
}

// ============================= xh precompute (R2-proven) =============================
#define XH_ROWS 16
#define XH_NTH  512
__global__ __launch_bounds__(XH_NTH, 4)
void xh_gemm(const float* __restrict__ x, const float* __restrict__ Wxh,
             const float* __restrict__ bias, _Float16* __restrict__ xh)
{
    const int j = threadIdx.x;
    const size_t r0 = (size_t)blockIdx.x * XH_ROWS;
    float wcol[IDIM];
#pragma unroll
    for (int i = 0; i < IDIM; ++i) wcol[i] = Wxh[(size_t)i * HDIM + j];
    const float bj = bias[j];
#pragma unroll
    for (int r = 0; r < XH_ROWS; ++r) {
        const float* xr = x + (r0 + r) * IDIM;
        float acc = bj;
#pragma unroll
        for (int i = 0; i < IDIM; ++i) acc += xr[i] * wcol[i];
        xh[(r0 + r) * HDIM + j] = (_Float16)acc;
    }
}

// ============================= MFMA recurrent kernel (4 fat waves) =============================
__global__ __attribute__((amdgpu_flat_work_group_size(NTH, NTH), amdgpu_waves_per_eu(1, 1)))
void rnn_mfma4(const _Float16* __restrict__ xh,  // (B*T, H) fp16, bias folded
               const float* __restrict__ Whh,    // (H,H) row-major [k][n]
               const float* __restrict__ fcw,    // (1,H)
               const float* __restrict__ fcb,    // (1)
               float* __restrict__ out)          // (B,1)
{
    extern __shared__ char smem[];
    char*     ldsW = smem;
    _Float16* hb   = reinterpret_cast<_Float16*>(smem + HB_OFF);
    float*    red  = reinterpret_cast<float*>(smem + RED_OFF);

    const int tid  = threadIdx.x;
    const int w    = tid >> 6;       // wave 0..3
    const int lane = tid & 63;
    const int l15  = lane & 15;
    const int quad = lane >> 4;
    const int b    = blockIdx.x;

    // ---- Prologue: gather B-frags (W column slices, validated R5 layout) ----
    // frag(nt,kt): lane holds B[k = 32*kt + quad*8 + jj][n = 128w + 16nt + l15]
    half8_t breg[NT][RKT];
#pragma unroll
    for (int nt = 0; nt < NT; ++nt) {
        const int col = 128 * w + 16 * nt + l15;
#pragma unroll
        for (int kt = 0; kt < KT; ++kt) {
            const int k0 = 32 * kt + quad * 8;
            H8U u;
#pragma unroll
            for (int jj = 0; jj < 8; ++jj)
                u.e[jj] = (_Float16)Whh[(size_t)(k0 + jj) * HDIM + col];
            if (kt < RKT) {
                breg[nt][kt] = u.v;
            } else {
                *reinterpret_cast<uint4*>(
                    ldsW + (size_t)((((w * NT + nt) * LKT) + (kt - RKT)) * 64 + lane) * 16) = u.u4;
            }
        }
    }

    // ---- init h slot 0 = 0 ----
    if (tid < HDIM / 2) {            // 256 threads x 2 halfs
        reinterpret_cast<half2_t*>(hb)[tid] = (half2_t){(_Float16)0.0f, (_Float16)0.0f};
    }
    __syncthreads();

    const _Float16* xhrow = xh + (size_t)b * TSTEPS * HDIM;

    float hout[NT];
#pragma unroll
    for (int nt = 0; nt < NT; ++nt) hout[nt] = 0.0f;

    for (int t = 0; t < TSTEPS; ++t) {
        const int cur = t & 1;
        const int nxt = cur ^ 1;

        // prefetch this step's xh (consumed after the MFMA block)
        _Float16 xv[NT];
#pragma unroll
        for (int nt = 0; nt < NT; ++nt)
            xv[nt] = xhrow[t * HDIM + 128 * w + 16 * nt + l15];

        float4_t acc[NT];
#pragma unroll
        for (int nt = 0; nt < NT; ++nt) acc[nt] = (float4_t){0.f, 0.f, 0.f, 0.f};

        // A-frag: lane holds A[m=l15][k = 32*kt + quad*8 + jj]; M=1 -> address ignores
        // l15 (16-way LDS broadcast, conflict-free). Validated in R5.
        const char* abase = smem + HB_OFF + cur * 1024 + quad * 16;

#pragma unroll
        for (int kt = 0; kt < RKT; ++kt) {
            H8U a;
            a.u4 = *reinterpret_cast<const uint4*>(abase + kt * 64);
#pragma unroll
            for (int nt = 0; nt < NT; ++nt)
                acc[nt] = __builtin_amdgcn_mfma_f32_16x16x32_f16(a.v, breg[nt][kt], acc[nt], 0, 0, 0);
        }
#pragma unroll
        for (int ktl = 0; ktl < LKT; ++ktl) {
            H8U a;
            a.u4 = *reinterpret_cast<const uint4*>(abase + (RKT + ktl) * 64);
#pragma unroll
            for (int nt = 0; nt < NT; ++nt) {
                H8U bb;
                bb.u4 = *reinterpret_cast<const uint4*>(
                    ldsW + (size_t)((((w * NT + nt) * LKT) + ktl) * 64 + lane) * 16);
                acc[nt] = __builtin_amdgcn_mfma_f32_16x16x32_f16(a.v, bb.v, acc[nt], 0, 0, 0);
            }
        }

        // D row 0 lives in acc[nt][0] on lanes 0..15 (col = 128w + 16nt + lane).
#pragma unroll
        for (int nt = 0; nt < NT; ++nt)
            hout[nt] = fast_tanh(acc[nt][0] + (float)xv[nt]);

        if (lane < 16) {
#pragma unroll
            for (int nt = 0; nt < NT; ++nt)
                hb[nxt * HDIM + 128 * w + 16 * nt + lane] = (_Float16)hout[nt];
        }
        __syncthreads();
    }

    // ---- Epilogue: out[b] = sum h_T[j]*fcw[j] + fcb ----
    float partial = 0.0f;
    if (lane < 16) {
#pragma unroll
        for (int nt = 0; nt < NT; ++nt)
            partial += hout[nt] * fcw[128 * w + 16 * nt + lane];
    }
#pragma unroll
    for (int off = 32; off >= 1; off >>= 1)
        partial += __shfl_down(partial, off, 64);
    if (lane == 0) red[w] = partial;
    __syncthreads();
    if (tid == 0) {
        float s = 0.0f;
#pragma unroll
        for (int i = 0; i < WAVES; ++i) s += red[i];
        out[b] = s + fcb[0];
    }
}

// ============================= fused fallback (R2-proven, emergency only) =============================
#define F_NTH  512
#define F_RP   216
#define F_RC   54
#define F_LC   18
#define F_LSTR 19
#define F_LDSW_BYTES (512 * F_LSTR * 16)
#define F_HBUF_OFF   F_LDSW_BYTES
#define F_HBUF_ELEMS 640
#define F_RED_OFF    (F_HBUF_OFF + 2 * F_HBUF_ELEMS * 2)
#define F_SMEM_BYTES (F_RED_OFF + 64)

__device__ __forceinline__ float fdot2(half2_t a, half2_t b, float c) {
#if __has_builtin(__builtin_amdgcn_fdot2)
    return __builtin_amdgcn_fdot2(a, b, c, false);
#else
    return c + (float)a[0] * (float)b[0] + (float)a[1] * (float)b[1];
#endif
}

__device__ __forceinline__ float ldW(const float* __restrict__ Whh,
                                     const float* __restrict__ Wxh, int k, int j) {
    return k < HDIM ? Whh[(size_t)k * HDIM + j] : Wxh[(size_t)(k - HDIM) * HDIM + j];
}

__global__ __attribute__((amdgpu_flat_work_group_size(F_NTH, F_NTH), amdgpu_waves_per_eu(2, 2)))
void rnn_fused(const float* __restrict__ x, const float* __restrict__ Wxh,
               const float* __restrict__ Whh, const float* __restrict__ bias,
               const float* __restrict__ fcw, const float* __restrict__ fcb,
               float* __restrict__ out)
{
    extern __shared__ char smem[];
    uint4*    ldsW = reinterpret_cast<uint4*>(smem);
    _Float16* hbuf = reinterpret_cast<_Float16*>(smem + F_HBUF_OFF);
    float*    red  = reinterpret_cast<float*>(smem + F_RED_OFF);

    const int j = threadIdx.x;
    const int b = blockIdx.x;

    half2_t wreg[F_RP];
#pragma unroll
    for (int p = 0; p < F_RP; ++p) {
        const int k = 2 * p;
        half2_t wv;
        wv[0] = (_Float16)Whh[(size_t)k * HDIM + j];
        wv[1] = (_Float16)Whh[(size_t)(k + 1) * HDIM + j];
        wreg[p] = wv;
    }
#pragma unroll
    for (int cc = 0; cc < F_LC; ++cc) {
        H8U u;
#pragma unroll
        for (int q = 0; q < 4; ++q) {
            const int k0 = 432 + 8 * cc + 2 * q;
            half2_t wv;
            wv[0] = (_Float16)ldW(Whh, Wxh, k0, j);
            wv[1] = (_Float16)ldW(Whh, Wxh, k0 + 1, j);
            u.p[q] = wv;
        }
        ldsW[j * F_LSTR + cc] = u.u4;
    }

    const float bj   = bias[j];
    const float fcwj = fcw[j];

    hbuf[j] = (_Float16)0.0f;
    if (j < IDIM) hbuf[HDIM + j] = (_Float16)x[((size_t)b * TSTEPS + 0) * IDIM + j];
    __syncthreads();

    float hval = 0.0f;
    for (int t = 0; t < TSTEPS; ++t) {
        const int cur = t & 1;
        const int nxt = cur ^ 1;
        const _Float16* hbp = hbuf + cur * F_HBUF_ELEMS;

        float xvv = 0.0f;
        const bool do_x = (j < IDIM) && (t + 1 < TSTEPS);
        if (do_x) xvv = x[((size_t)b * TSTEPS + (t + 1)) * IDIM + j];

        float a0 = bj, a1 = 0.0f, a2 = 0.0f, a3 = 0.0f;
#pragma unroll
        for (int c = 0; c < F_RC; ++c) {
            H8U u;
            u.v = *reinterpret_cast<const half8_t*>(hbp + 8 * c);
            a0 = fdot2(u.p[0], wreg[4 * c + 0], a0);
            a1 = fdot2(u.p[1], wreg[4 * c + 1], a1);
            a2 = fdot2(u.p[2], wreg[4 * c + 2], a2);
            a3 = fdot2(u.p[3], wreg[4 * c + 3], a3);
        }
#pragma unroll
        for (int cc = 0; cc < F_LC; ++cc) {
            H8U u, wv;
            u.v   = *reinterpret_cast<const half8_t*>(hbp + 8 * (F_RC + cc));
            wv.u4 = ldsW[j * F_LSTR + cc];
            a0 = fdot2(u.p[0], wv.p[0], a0);
            a1 = fdot2(u.p[1], wv.p[1], a1);
            a2 = fdot2(u.p[2], wv.p[2], a2);
            a3 = fdot2(u.p[3], wv.p[3], a3);
        }
        hval = fast_tanh((a0 + a1) + (a2 + a3));

        hbuf[nxt * F_HBUF_ELEMS + j] = (_Float16)hval;
        if (do_x) hbuf[nxt * F_HBUF_ELEMS + HDIM + j] = (_Float16)xvv;
        __syncthreads();
    }

    float partial = hval * fcwj;
#pragma unroll
    for (int off = 32; off >= 1; off >>= 1)
        partial += __shfl_down(partial, off, 64);
    if ((j & 63) == 0) red[j >> 6] = partial;
    __syncthreads();
    if (j == 0) {
        float s = 0.0f;
#pragma unroll
        for (int wv = 0; wv < 8; ++wv) s += red[wv];
        out[b] = s + fcb[0];
    }
}

// ============================= host =============================
extern "C" void kernel_launch(void* const* d_in, const int* in_sizes, int n_in,
                              void* d_out, int out_size, void* d_ws, size_t ws_size,
                              hipStream_t stream) {
    const float* x    = (const float*)d_in[0];
    const float* Wxh  = (const float*)d_in[1];
    const float* Whh  = (const float*)d_in[2];
    const float* bias = (const float*)d_in[3];
    const float* fcw  = (const float*)d_in[4];
    const float* fcb  = (const float*)d_in[5];
    float* out = (float*)d_out;

    const size_t xh_bytes = (size_t)BATCH * TSTEPS * HDIM * sizeof(_Float16);  // 134 MB
    if (ws_size >= xh_bytes) {
        hipFuncSetAttribute(reinterpret_cast<const void*>(rnn_mfma4),
                            hipFuncAttributeMaxDynamicSharedMemorySize, SMEM_BYTES);
        _Float16* xh = (_Float16*)d_ws;
        xh_gemm<<<(BATCH * TSTEPS) / XH_ROWS, XH_NTH, 0, stream>>>(x, Wxh, bias, xh);
        rnn_mfma4<<<BATCH, NTH, SMEM_BYTES, stream>>>(xh, Whh, fcw, fcb, out);
    } else {
        hipFuncSetAttribute(reinterpret_cast<const void*>(rnn_fused),
                            hipFuncAttributeMaxDynamicSharedMemorySize, F_SMEM_BYTES);
        rnn_fused<<<BATCH, F_NTH, F_SMEM_BYTES, stream>>>(x, Wxh, Whh, bias, fcw, fcb, out);
    }
}

// Round 7
// 1425.937 us; speedup vs baseline: 1.6229x; 1.6229x over previous
//
#include <hip/hip_runtime.h>

// B=256, T=512, I=64, H=512.  h_t = tanh(xh_t + h@Whh); out = h_T@fc_w.T + fc_b
//
// R7 "rnn_mfma_g": R5 (905us) was LDS-pipe bound: 256 KB/step/CU (A-frag delivery 128 KB
// + LDS-resident B 128 KB) at ~100 B/cyc ~= 2-3k cyc/step vs 620 cyc MFMA issue.
// Whh is block-invariant => stream most of the non-register B share down the VMEM pipe
// from a fragment-ordered global buffer (L2-hot: 96 KB working set per XCD).
// B k-tile split: 12 regs (R5-proven) + 1 LDS (32 KB/step) + 3 global (96 KB/step, VMEM).
// Pipes then balance: LDS ~160 KB (~1600cyc) || L2 ~96 KB (~1750cyc) || MFMA 620cyc.
// 8 waves, waves_per_eu(2,2) = the calibrated spill-free config (R2..R6 evidence:
// usable budget is 128 arch + 128 AGPR; ~240 live values max; 1 wave/SIMD (R6) exposes
// all latency AND spills).

#define BATCH    256
#define TSTEPS   512
#define IDIM     64
#define HDIM     512
#define NTH      512
#define WAVES    8
#define NT       4            // n-tiles per wave (16 cols each) -> 64 cols/wave
#define RKT      12           // k-tiles with B-frags in registers (kt 0..11)
#define LKTI     12           // the single LDS-resident k-tile index (kt 12)
#define GKT      3            // k-tiles streamed from global (kt 13..15)
#define KT       16

#define LDSB_BYTES (WAVES * NT * 64 * 16)         // 32768 (kt=12 B-frags)
#define HB_OFF     LDSB_BYTES
#define RED_OFF    (HB_OFF + 2 * HDIM * 2)        // 2x512 fp16 h dbuf
#define SMEM_BYTES (RED_OFF + 64)                 // 34880

#define GFRAG_ELEMS (WAVES * NT * GKT * 64)       // 6144 uint4 = 96 KB

typedef _Float16 half2_t  __attribute__((ext_vector_type(2)));
typedef _Float16 half8_t  __attribute__((ext_vector_type(8)));
typedef float    float4_t __attribute__((ext_vector_type(4)));

union H8U {
    half8_t  v;
    half2_t  p[4];
    uint4    u4;
    _Float16 e[8];
};

__device__ __forceinline__ float fast_tanh(float x) {
    float e = __builtin_amdgcn_exp2f(x * 2.88539008177792681472f);
    return 1.0f - 2.0f * __builtin_amdgcn_rcpf(e + 1.0f);
}

// ============================= xh precompute (R2-proven) =============================
#define XH_ROWS 16
#define XH_NTH  512
__global__ __launch_bounds__(XH_NTH, 4)
void xh_gemm(const float* __restrict__ x, const float* __restrict__ Wxh,
             const float* __restrict__ bias, _Float16* __restrict__ xh)
{
    const int j = threadIdx.x;
    const size_t r0 = (size_t)blockIdx.x * XH_ROWS;
    float wcol[IDIM];
#pragma unroll
    for (int i = 0; i < IDIM; ++i) wcol[i] = Wxh[(size_t)i * HDIM + j];
    const float bj = bias[j];
#pragma unroll
    for (int r = 0; r < XH_ROWS; ++r) {
        const float* xr = x + (r0 + r) * IDIM;
        float acc = bj;
#pragma unroll
        for (int i = 0; i < IDIM; ++i) acc += xr[i] * wcol[i];
        xh[(r0 + r) * HDIM + j] = (_Float16)acc;
    }
}

// ============================= B-fragment prep (kt 13..15 -> global, frag order) ======
// tile tIdx = (w*NT + nt)*GKT + g  maps to kt = 13+g, cols 64w+16nt+0..15.
// element [tIdx*64 + lane] holds B[k = 32*kt + (lane>>4)*8 + jj][col = 64w+16nt+(lane&15)]
__global__ __launch_bounds__(256)
void bfrag_prep(const float* __restrict__ Whh, uint4* __restrict__ gfrag)
{
    const int gid  = blockIdx.x * 256 + threadIdx.x;   // 0..6143
    const int lane = gid & 63;
    const int tIdx = gid >> 6;
    const int g    = tIdx % GKT;
    const int nt   = (tIdx / GKT) % NT;
    const int w    = tIdx / (GKT * NT);
    const int col  = 64 * w + 16 * nt + (lane & 15);
    const int k0   = 32 * (13 + g) + (lane >> 4) * 8;
    H8U u;
#pragma unroll
    for (int jj = 0; jj < 8; ++jj)
        u.e[jj] = (_Float16)Whh[(size_t)(k0 + jj) * HDIM + col];
    gfrag[gid] = u.u4;
}

// ============================= MFMA recurrent kernel =============================
__global__ __attribute__((amdgpu_flat_work_group_size(NTH, NTH), amdgpu_waves_per_eu(2, 2)))
void rnn_mfma_g(const _Float16* __restrict__ xh,  // (B*T, H) fp16, bias folded
                const float* __restrict__ Whh,    // (H,H) row-major [k][n]
                const uint4* __restrict__ gfrag,  // 6144 frags (kt 13..15), block-invariant
                const float* __restrict__ fcw,    // (1,H)
                const float* __restrict__ fcb,    // (1)
                float* __restrict__ out)          // (B,1)
{
    extern __shared__ char smem[];
    char*     ldsB = smem;
    _Float16* hb   = reinterpret_cast<_Float16*>(smem + HB_OFF);
    float*    red  = reinterpret_cast<float*>(smem + RED_OFF);

    const int tid  = threadIdx.x;
    const int w    = tid >> 6;
    const int lane = tid & 63;
    const int l15  = lane & 15;
    const int quad = lane >> 4;
    const int b    = blockIdx.x;

    // ---- Prologue: B-frags kt 0..11 into registers, kt 12 into LDS (R5-validated layout)
    half8_t breg[NT][RKT];
#pragma unroll
    for (int nt = 0; nt < NT; ++nt) {
        const int col = 64 * w + 16 * nt + l15;
#pragma unroll
        for (int kt = 0; kt <= RKT; ++kt) {
            const int k0 = 32 * kt + quad * 8;
            H8U u;
#pragma unroll
            for (int jj = 0; jj < 8; ++jj)
                u.e[jj] = (_Float16)Whh[(size_t)(k0 + jj) * HDIM + col];
            if (kt < RKT) {
                breg[nt][kt] = u.v;
            } else {  // kt == 12
                *reinterpret_cast<uint4*>(
                    ldsB + (size_t)((w * NT + nt) * 64 + lane) * 16) = u.u4;
            }
        }
    }

    // ---- init h slot 0 = 0 ----
    hb[tid] = (_Float16)0.0f;
    __syncthreads();

    const _Float16* xhrow = xh + (size_t)b * TSTEPS * HDIM;

    float hout[NT] = {0.f, 0.f, 0.f, 0.f};
    for (int t = 0; t < TSTEPS; ++t) {
        const int cur = t & 1;
        const int nxt = cur ^ 1;

        // Launder gfrag base per step: wave-uniform + opaque => no LICM hoist of the
        // loop-invariant frag loads (would cost 48 regs), SMEM-friendly addressing.
        unsigned lo = __builtin_amdgcn_readfirstlane((unsigned)(uintptr_t)gfrag);
        unsigned hi = __builtin_amdgcn_readfirstlane((unsigned)((uintptr_t)gfrag >> 32));
        const uint4* gf = (const uint4*)((((uintptr_t)hi) << 32) | (uintptr_t)lo);

        // Prefetch g=0 global B-frags (consumed after 48 reg-MFMAs ~> latency hidden).
        H8U gb[2][NT];
#pragma unroll
        for (int nt = 0; nt < NT; ++nt)
            gb[0][nt].u4 = gf[((w * NT + nt) * GKT + 0) * 64 + lane];

        // prefetch this step's xh
        _Float16 xv[NT];
#pragma unroll
        for (int nt = 0; nt < NT; ++nt)
            xv[nt] = xhrow[t * HDIM + 64 * w + 16 * nt + l15];

        float4_t acc[NT];
#pragma unroll
        for (int nt = 0; nt < NT; ++nt) acc[nt] = (float4_t){0.f, 0.f, 0.f, 0.f};

        // A-frag: lane holds A[m=l15][k = 32*kt + quad*8 + jj]; M=1 -> address ignores
        // l15 (16-way broadcast, conflict-free). R5-validated.
        const char* abase = smem + HB_OFF + cur * 1024 + quad * 16;

        // kt 0..11: B from registers
#pragma unroll
        for (int kt = 0; kt < RKT; ++kt) {
            H8U a;
            a.u4 = *reinterpret_cast<const uint4*>(abase + kt * 64);
#pragma unroll
            for (int nt = 0; nt < NT; ++nt)
                acc[nt] = __builtin_amdgcn_mfma_f32_16x16x32_f16(a.v, breg[nt][kt], acc[nt], 0, 0, 0);
        }
        // kt 12: B from LDS
        {
            H8U a;
            a.u4 = *reinterpret_cast<const uint4*>(abase + LKTI * 64);
#pragma unroll
            for (int nt = 0; nt < NT; ++nt) {
                H8U bb;
                bb.u4 = *reinterpret_cast<const uint4*>(
                    ldsB + (size_t)((w * NT + nt) * 64 + lane) * 16);
                acc[nt] = __builtin_amdgcn_mfma_f32_16x16x32_f16(a.v, bb.v, acc[nt], 0, 0, 0);
            }
        }
        // kt 13..15: B from global (L1/L2-hot), double-prefetched
#pragma unroll
        for (int g = 0; g < GKT; ++g) {
            if (g + 1 < GKT) {
#pragma unroll
                for (int nt = 0; nt < NT; ++nt)
                    gb[(g + 1) & 1][nt].u4 = gf[((w * NT + nt) * GKT + (g + 1)) * 64 + lane];
            }
            H8U a;
            a.u4 = *reinterpret_cast<const uint4*>(abase + (13 + g) * 64);
#pragma unroll
            for (int nt = 0; nt < NT; ++nt)
                acc[nt] = __builtin_amdgcn_mfma_f32_16x16x32_f16(a.v, gb[g & 1][nt].v, acc[nt], 0, 0, 0);
        }

        // D row 0 lives in acc[nt][0] on lanes 0..15 (col = 64w+16nt+lane).
#pragma unroll
        for (int nt = 0; nt < NT; ++nt)
            hout[nt] = fast_tanh(acc[nt][0] + (float)xv[nt]);

        if (lane < 16) {
#pragma unroll
            for (int nt = 0; nt < NT; ++nt)
                hb[nxt * HDIM + 64 * w + 16 * nt + lane] = (_Float16)hout[nt];
        }
        __syncthreads();
    }

    // ---- Epilogue ----
    float partial = 0.0f;
    if (lane < 16) {
#pragma unroll
        for (int nt = 0; nt < NT; ++nt)
            partial += hout[nt] * fcw[64 * w + 16 * nt + lane];
    }
#pragma unroll
    for (int off = 32; off >= 1; off >>= 1)
        partial += __shfl_down(partial, off, 64);
    if (lane == 0) red[w] = partial;
    __syncthreads();
    if (tid == 0) {
        float s = 0.0f;
#pragma unroll
        for (int i = 0; i < WAVES; ++i) s += red[i];
        out[b] = s + fcb[0];
    }
}

// ============================= fused fallback (R2-proven, emergency only) =============================
#define F_NTH  512
#define F_RP   216
#define F_RC   54
#define F_LC   18
#define F_LSTR 19
#define F_LDSW_BYTES (512 * F_LSTR * 16)
#define F_HBUF_OFF   F_LDSW_BYTES
#define F_HBUF_ELEMS 640
#define F_RED_OFF    (F_HBUF_OFF + 2 * F_HBUF_ELEMS * 2)
#define F_SMEM_BYTES (F_RED_OFF + 64)

__device__ __forceinline__ float fdot2(half2_t a, half2_t b, float c) {
#if __has_builtin(__builtin_amdgcn_fdot2)
    return __builtin_amdgcn_fdot2(a, b, c, false);
#else
    return c + (float)a[0] * (float)b[0] + (float)a[1] * (float)b[1];
#endif
}

__device__ __forceinline__ float ldW(const float* __restrict__ Whh,
                                     const float* __restrict__ Wxh, int k, int j) {
    return k < HDIM ? Whh[(size_t)k * HDIM + j] : Wxh[(size_t)(k - HDIM) * HDIM + j];
}

__global__ __attribute__((amdgpu_flat_work_group_size(F_NTH, F_NTH), amdgpu_waves_per_eu(2, 2)))
void rnn_fused(const float* __restrict__ x, const float* __restrict__ Wxh,
               const float* __restrict__ Whh, const float* __restrict__ bias,
               const float* __restrict__ fcw, const float* __restrict__ fcb,
               float* __restrict__ out)
{
    extern __shared__ char smem[];
    uint4*    ldsW = reinterpret_cast<uint4*>(smem);
    _Float16* hbuf = reinterpret_cast<_Float16*>(smem + F_HBUF_OFF);
    float*    red  = reinterpret_cast<float*>(smem + F_RED_OFF);

    const int j = threadIdx.x;
    const int b = blockIdx.x;

    half2_t wreg[F_RP];
#pragma unroll
    for (int p = 0; p < F_RP; ++p) {
        const int k = 2 * p;
        half2_t wv;
        wv[0] = (_Float16)Whh[(size_t)k * HDIM + j];
        wv[1] = (_Float16)Whh[(size_t)(k + 1) * HDIM + j];
        wreg[p] = wv;
    }
#pragma unroll
    for (int cc = 0; cc < F_LC; ++cc) {
        H8U u;
#pragma unroll
        for (int q = 0; q < 4; ++q) {
            const int k0 = 432 + 8 * cc + 2 * q;
            half2_t wv;
            wv[0] = (_Float16)ldW(Whh, Wxh, k0, j);
            wv[1] = (_Float16)ldW(Whh, Wxh, k0 + 1, j);
            u.p[q] = wv;
        }
        ldsW[j * F_LSTR + cc] = u.u4;
    }

    const float bj   = bias[j];
    const float fcwj = fcw[j];

    hbuf[j] = (_Float16)0.0f;
    if (j < IDIM) hbuf[HDIM + j] = (_Float16)x[((size_t)b * TSTEPS + 0) * IDIM + j];
    __syncthreads();

    float hval = 0.0f;
    for (int t = 0; t < TSTEPS; ++t) {
        const int cur = t & 1;
        const int nxt = cur ^ 1;
        const _Float16* hbp = hbuf + cur * F_HBUF_ELEMS;

        float xvv = 0.0f;
        const bool do_x = (j < IDIM) && (t + 1 < TSTEPS);
        if (do_x) xvv = x[((size_t)b * TSTEPS + (t + 1)) * IDIM + j];

        float a0 = bj, a1 = 0.0f, a2 = 0.0f, a3 = 0.0f;
#pragma unroll
        for (int c = 0; c < F_RC; ++c) {
            H8U u;
            u.v = *reinterpret_cast<const half8_t*>(hbp + 8 * c);
            a0 = fdot2(u.p[0], wreg[4 * c + 0], a0);
            a1 = fdot2(u.p[1], wreg[4 * c + 1], a1);
            a2 = fdot2(u.p[2], wreg[4 * c + 2], a2);
            a3 = fdot2(u.p[3], wreg[4 * c + 3], a3);
        }
#pragma unroll
        for (int cc = 0; cc < F_LC; ++cc) {
            H8U u, wv;
            u.v   = *reinterpret_cast<const half8_t*>(hbp + 8 * (F_RC + cc));
            wv.u4 = ldsW[j * F_LSTR + cc];
            a0 = fdot2(u.p[0], wv.p[0], a0);
            a1 = fdot2(u.p[1], wv.p[1], a1);
            a2 = fdot2(u.p[2], wv.p[2], a2);
            a3 = fdot2(u.p[3], wv.p[3], a3);
        }
        hval = fast_tanh((a0 + a1) + (a2 + a3));

        hbuf[nxt * F_HBUF_ELEMS + j] = (_Float16)hval;
        if (do_x) hbuf[nxt * F_HBUF_ELEMS + HDIM + j] = (_Float16)xvv;
        __syncthreads();
    }

    float partial = hval * fcwj;
#pragma unroll
    for (int off = 32; off >= 1; off >>= 1)
        partial += __shfl_down(partial, off, 64);
    if ((j & 63) == 0) red[j >> 6] = partial;
    __syncthreads();
    if (j == 0) {
        float s = 0.0f;
#pragma unroll
        for (int wv = 0; wv < 8; ++wv) s += red[wv];
        out[b] = s + fcb[0];
    }
}

// ============================= host =============================
extern "C" void kernel_launch(void* const* d_in, const int* in_sizes, int n_in,
                              void* d_out, int out_size, void* d_ws, size_t ws_size,
                              hipStream_t stream) {
    const float* x    = (const float*)d_in[0];
    const float* Wxh  = (const float*)d_in[1];
    const float* Whh  = (const float*)d_in[2];
    const float* bias = (const float*)d_in[3];
    const float* fcw  = (const float*)d_in[4];
    const float* fcb  = (const float*)d_in[5];
    float* out = (float*)d_out;

    const size_t xh_bytes    = (size_t)BATCH * TSTEPS * HDIM * sizeof(_Float16);  // 134 MB
    const size_t gfrag_bytes = (size_t)GFRAG_ELEMS * sizeof(uint4);               // 96 KB

    if (ws_size >= xh_bytes + gfrag_bytes) {
        hipFuncSetAttribute(reinterpret_cast<const void*>(rnn_mfma_g),
                            hipFuncAttributeMaxDynamicSharedMemorySize, SMEM_BYTES);
        _Float16* xh    = (_Float16*)d_ws;
        uint4*    gfrag = (uint4*)((char*)d_ws + xh_bytes);
        xh_gemm<<<(BATCH * TSTEPS) / XH_ROWS, XH_NTH, 0, stream>>>(x, Wxh, bias, xh);
        bfrag_prep<<<GFRAG_ELEMS / 256, 256, 0, stream>>>(Whh, gfrag);
        rnn_mfma_g<<<BATCH, NTH, SMEM_BYTES, stream>>>(xh, Whh, gfrag, fcw, fcb, out);
    } else {
        hipFuncSetAttribute(reinterpret_cast<const void*>(rnn_fused),
                            hipFuncAttributeMaxDynamicSharedMemorySize, F_SMEM_BYTES);
        rnn_fused<<<BATCH, F_NTH, F_SMEM_BYTES, stream>>>(x, Wxh, Whh, bias, fcw, fcb, out);
    }
}